// Round 6
// baseline (164.528 us; speedup 1.0000x reference)
//
#include <hip/hip_runtime.h>
#include <stdint.h>

#pragma clang fp contract(off)

#define A_TOTAL 147456   // 128*128*9
#define G 256

// Base anchors (base_size=16, ratios {0.5,1,2}, scales {8,16,32}) — from
// reference _base_anchors() (np.round half-to-even: 11.5->12).
__constant__ float c_bx1[9] = { -84.f, -176.f, -360.f,  -56.f, -120.f, -248.f,  -36.f,  -80.f, -168.f };
__constant__ float c_by1[9] = { -40.f,  -88.f, -184.f,  -56.f, -120.f, -248.f,  -80.f, -168.f, -344.f };
__constant__ float c_bx2[9] = {  99.f,  191.f,  375.f,   71.f,  135.f,  263.f,   51.f,   95.f,  183.f };
__constant__ float c_by2[9] = {  55.f,  103.f,  199.f,   71.f,  135.f,  263.f,   95.f,  183.f,  359.f };
__constant__ float c_area[9] = { 17664.f, 70656.f, 282624.f, 16384.f, 65536.f, 262144.f, 15488.f, 61952.f, 247808.f };

// slot init: iou = +0.0 (fenc = 0x80000000), g = 0 (~g = 0xFFFFFFFF).
// Under u64 max this loses to any iou > 0 and wins ties vs any g > 0 —
// exactly jnp.argmax first-occurrence over an all-zero-except-scattered row.
#define SLOT_INIT 0x80000000FFFFFFFFULL

__device__ __forceinline__ unsigned int fenc(float f) {
    unsigned int u = __float_as_uint(f);
    return (u & 0x80000000u) ? ~u : (u | 0x80000000u);
}

__device__ __forceinline__ unsigned long long shfl_down_u64(unsigned long long v, int off) {
    unsigned int lo = (unsigned int)v;
    unsigned int hi = (unsigned int)(v >> 32);
    lo = __shfl_down(lo, off, 64);
    hi = __shfl_down(hi, off, 64);
    return ((unsigned long long)hi << 32) | lo;
}

// K0: init per-anchor slots (ws is poisoned 0xAA each run — would win maxes).
__global__ __launch_bounds__(256) void k_init(unsigned long long* __restrict__ slots)
{
    const int i = blockIdx.x * 256 + threadIdx.x;
    slots[i] = SLOT_INIT;
}

// K1: one block per gt. Rasterize the gt's dilated anchor window (all cells
// where inter could be > 0; NO inside clamp — per-anchor max is unmasked),
// compute the exact reference iou once per (anchor,gt) pair, and:
//  (a) atomicMax-scatter (fenc(iou)<<32)|~g into the anchor's slot,
//  (b) block-reduce the inside-masked encode -> win[g] (gt-argmax direction).
// Pairs outside the window have inter == 0 exactly -> iou 0 -> dominated by
// SLOT_INIT; the masked winner has iou > 0 and is provably in-window.
__global__ __launch_bounds__(256) void k_scatter(
    const float* __restrict__ gt, const float* __restrict__ meta,
    unsigned long long* __restrict__ slots, int* __restrict__ win)
{
    __shared__ unsigned long long red[4];
    const int g = blockIdx.x;
    const float gx1 = gt[4*g+0], gy1 = gt[4*g+1], gx2 = gt[4*g+2], gy2 = gt[4*g+3];
    const float area_b = (gx2 - gx1 + 1.0f) * (gy2 - gy1 + 1.0f);
    const float H = meta[0], W = meta[1];
    const int tx = threadIdx.x & 15, ty = threadIdx.x >> 4;
    const unsigned int ng = ~(unsigned int)g;

    constexpr int ibx1[9] = {-84,-176,-360,-56,-120,-248,-36,-80,-168};
    constexpr int iby1[9] = {-40,-88,-184,-56,-120,-248,-80,-168,-344};
    constexpr int ibx2[9] = { 99, 191, 375, 71, 135, 263, 51, 95, 183};
    constexpr int iby2[9] = { 55, 103, 199, 71, 135, 263, 95, 183, 359};
    constexpr int iarea[9] = {17664,70656,282624,16384,65536,262144,15488,61952,247808};

    unsigned long long best = 0ULL;  // < any real masked encoding
    #pragma unroll
    for (int a = 0; a < 9; ++a) {
        // window of cells where iw/ih could be > 0, padded 1, clipped to grid
        int xlo = max((int)floorf((gx1 - (float)ibx2[a]) * 0.0625f) - 1, 0);
        int xhi = min((int)floorf((gx2 - (float)ibx1[a]) * 0.0625f) + 1, 127);
        int ylo = max((int)floorf((gy1 - (float)iby2[a]) * 0.0625f) - 1, 0);
        int yhi = min((int)floorf((gy2 - (float)iby1[a]) * 0.0625f) + 1, 127);
        const float fa = (float)iarea[a];

        for (int iy = ylo + ty; iy <= yhi; iy += 16) {
            const float ay1 = (float)((iy << 4) + iby1[a]);
            const float ay2 = (float)((iy << 4) + iby2[a]);
            float ih = fminf(ay2, gy2) - fmaxf(ay1, gy1) + 1.0f; ih = fmaxf(ih, 0.0f);
            for (int ix = xlo + tx; ix <= xhi; ix += 16) {
                const float ax1 = (float)((ix << 4) + ibx1[a]);
                const float ax2 = (float)((ix << 4) + ibx2[a]);
                float iw = fminf(ax2, gx2) - fmaxf(ax1, gx1) + 1.0f; iw = fmaxf(iw, 0.0f);
                float inter = iw * ih;
                float uni = fmaxf(fa + area_b - inter, 1e-8f);
                float iou = inter / uni;   // exact ref arithmetic
                int n = ((iy << 7) + ix) * 9 + a;
                if (inter > 0.0f) {
                    // per-anchor direction (unmasked); fire-and-forget
                    atomicMax(&slots[n],
                              ((unsigned long long)fenc(iou) << 32) | ng);
                }
                // per-gt direction (masked by inside)
                bool inside = (ax1 >= 0.0f) & (ay1 >= 0.0f) & (ax2 < W) & (ay2 < H);
                float m = inside ? iou : -1.0f;
                unsigned long long e =
                    ((unsigned long long)fenc(m) << 32) | (unsigned int)(~n);
                if (e > best) best = e;
            }
        }
    }

    for (int off = 32; off >= 1; off >>= 1) {
        unsigned long long o = shfl_down_u64(best, off);
        if (o > best) best = o;
    }
    const int wave = threadIdx.x >> 6, lane = threadIdx.x & 63;
    if (lane == 0) red[wave] = best;
    __syncthreads();
    if (threadIdx.x == 0) {
        unsigned long long v = red[0];
        if (red[1] > v) v = red[1];
        if (red[2] > v) v = red[2];
        if (red[3] > v) v = red[3];
        win[g] = (int)(~(unsigned int)(v & 0xffffffffULL));
    }
}

// K2: one thread per anchor, NO gt loop. Decode slot -> (max_overlap, argmax),
// label ladder (minus gt-argmax scatter; k_fix patches), bbox transform.
__global__ __launch_bounds__(256) void k_anchor(
    const float* __restrict__ gt, const float* __restrict__ meta,
    const unsigned long long* __restrict__ slots, float* __restrict__ out)
{
    __shared__ float4 sfull[G];
    const int tid = threadIdx.x;
    sfull[tid] = ((const float4*)gt)[tid];
    __syncthreads();

    const float H = meta[0], W = meta[1];
    const int n = blockIdx.x * 256 + tid;

    unsigned long long s = slots[n];
    // all stored ious are >= 0, so hi word = bits(iou) | 0x80000000
    float bestv = __uint_as_float((unsigned int)(s >> 32) & 0x7fffffffu);
    int barg = (int)(~(unsigned int)(s & 0xffffffffULL));

    int k = n / 9;
    int a = n - 9 * k;
    float sx = (float)((k & 127) << 4);
    float sy = (float)((k >> 7) << 4);
    float ax1 = sx + c_bx1[a];
    float ay1 = sy + c_by1[a];
    float ax2 = sx + c_bx2[a];
    float ay2 = sy + c_by2[a];
    bool inside = (ax1 >= 0.0f) & (ay1 >= 0.0f) & (ax2 < W) & (ay2 < H);

    // Label ladder minus the gt-argmax scatter (k_fix rewrites those anchors).
    float label = -1.0f;
    if (bestv < 0.3f) label = 0.0f;            // NEG_OVERLAP
    if (bestv >= 0.7f) label = 1.0f;           // POS_OVERLAP
    if (!inside) label = -1.0f;                // applied last

    float4 gb = sfull[barg];
    float ew = ax2 - ax1 + 1.0f;
    float eh = ay2 - ay1 + 1.0f;
    float ecx = ax1 + 0.5f * ew;
    float ecy = ay1 + 0.5f * eh;
    float gw = gb.z - gb.x + 1.0f;
    float gh = gb.w - gb.y + 1.0f;
    float gcx = gb.x + 0.5f * gw;
    float gcy = gb.y + 0.5f * gh;
    float t0 = (gcx - ecx) / ew;
    float t1 = (gcy - ecy) / eh;
    float t2 = logf(gw / ew);
    float t3 = logf(gh / eh);
    if (!inside) { t0 = 0.0f; t1 = 0.0f; t2 = 0.0f; t3 = 0.0f; }

    out[n] = label;
    ((float4*)(out + A_TOTAL))[n] = make_float4(t0, t1, t2, t3);
}

// K3: patch the 256 winner anchors (gt-argmax scatter-add). Winners are
// provably inside with iou > 0. gt + win staged in LDS (R3 lesson: global
// uniform reads from a single block are latency-bound).
__global__ __launch_bounds__(256) void k_fix(
    const float* __restrict__ gt, const int* __restrict__ win,
    float* __restrict__ out)
{
    __shared__ float4 sb[G];
    __shared__ float  sa[G];
    __shared__ int    swin[G];
    const int t = threadIdx.x;
    {
        float4 b = ((const float4*)gt)[t];
        sb[t] = b;
        sa[t] = (b.z - b.x + 1.0f) * (b.w - b.y + 1.0f);
        swin[t] = win[t];
    }
    __syncthreads();

    const int idx = swin[t];
    int k = idx / 9;
    int a = idx - 9 * k;
    float sx = (float)((k & 127) << 4);
    float sy = (float)((k >> 7) << 4);
    float ax1 = sx + c_bx1[a];
    float ay1 = sy + c_by1[a];
    float ax2 = sx + c_bx2[a];
    float ay2 = sy + c_by2[a];
    float area_a = c_area[a];

    float mo = -1.0f;
    int cnt = 0;
    #pragma unroll 4
    for (int g = 0; g < G; ++g) {
        float4 bb = sb[g];
        float iw = fminf(ax2, bb.z) - fmaxf(ax1, bb.x) + 1.0f; iw = fmaxf(iw, 0.0f);
        float ih = fminf(ay2, bb.w) - fmaxf(ay1, bb.y) + 1.0f; ih = fmaxf(ih, 0.0f);
        float inter = iw * ih;
        float uni = fmaxf(area_a + sa[g] - inter, 1e-8f);
        float iou = inter / uni;
        mo = fmaxf(mo, iou);
        cnt += (swin[g] == idx);
    }

    float label = -1.0f;
    if (mo < 0.3f) label = 0.0f;
    label = label + (float)cnt * (1.0f - label);   // .at[].add with duplicates
    if (mo >= 0.7f) label = 1.0f;

    out[idx] = label;
}

extern "C" void kernel_launch(void* const* d_in, const int* in_sizes, int n_in,
                              void* d_out, int out_size, void* d_ws, size_t ws_size,
                              hipStream_t stream) {
    // d_in[0] = scores (unused), d_in[1] = gt_boxes (1,256,4), d_in[2] = metadata (1,3)
    const float* gt   = (const float*)d_in[1];
    const float* meta = (const float*)d_in[2];
    float* out = (float*)d_out;
    unsigned long long* slots = (unsigned long long*)d_ws;   // 147456 * 8B
    int* win = (int*)(slots + A_TOTAL);                      // 256 ints

    k_init<<<A_TOTAL / 256, 256, 0, stream>>>(slots);
    k_scatter<<<G, 256, 0, stream>>>(gt, meta, slots, win);
    k_anchor<<<A_TOTAL / 256, 256, 0, stream>>>(gt, meta, slots, out);
    k_fix<<<1, 256, 0, stream>>>(gt, win, out);
}

// Round 7
// 90.910 us; speedup vs baseline: 1.8098x; 1.8098x over previous
//
#include <hip/hip_runtime.h>
#include <stdint.h>

#pragma clang fp contract(off)

#define A_TOTAL 147456   // 128*128*9
#define G 256
#define NANCHOR_BLOCKS 576          // 9 types x 64 tiles(16x16 cells)
#define TOTAL_BLOCKS (NANCHOR_BLOCKS + G)

// Base anchors (base_size=16, ratios {0.5,1,2}, scales {8,16,32}) — from
// reference _base_anchors() (np.round half-to-even: 11.5->12).
__constant__ float c_bx1[9] = { -84.f, -176.f, -360.f,  -56.f, -120.f, -248.f,  -36.f,  -80.f, -168.f };
__constant__ float c_by1[9] = { -40.f,  -88.f, -184.f,  -56.f, -120.f, -248.f,  -80.f, -168.f, -344.f };
__constant__ float c_bx2[9] = {  99.f,  191.f,  375.f,   71.f,  135.f,  263.f,   51.f,   95.f,  183.f };
__constant__ float c_by2[9] = {  55.f,  103.f,  199.f,   71.f,  135.f,  263.f,   95.f,  183.f,  359.f };
__constant__ float c_area[9] = { 17664.f, 70656.f, 282624.f, 16384.f, 65536.f, 262144.f, 15488.f, 61952.f, 247808.f };

__device__ __forceinline__ unsigned int fenc(float f) {
    unsigned int u = __float_as_uint(f);
    return (u & 0x80000000u) ? ~u : (u | 0x80000000u);
}

__device__ __forceinline__ unsigned long long shfl_down_u64(unsigned long long v, int off) {
    unsigned int lo = (unsigned int)v;
    unsigned int hi = (unsigned int)(v >> 32);
    lo = __shfl_down(lo, off, 64);
    hi = __shfl_down(hi, off, 64);
    return ((unsigned long long)hi << 32) | lo;
}

// Fused kernel.
//  Blocks [0,576): per-anchor path. Block b owns anchor type a=b>>6 over a
//    16x16-cell tile (type-uniform waves: scalar base coords, type-specific
//    gt cull, uniform trip count, wave-level zero-skip).
//  Blocks [576,832): per-gt argmax over inside anchors (windowed) -> win[].
__global__ __launch_bounds__(256) void k_fused(
    const float* __restrict__ gt, const float* __restrict__ meta,
    int* __restrict__ win, float* __restrict__ out)
{
    __shared__ float4 sbox[G];      // survivor boxes, ascending original g
    __shared__ int    sg[G];        // survivor original index
    __shared__ int    wcnt[4], woff[4], sS;
    __shared__ float4 sg0;          // gt[0] (fallback when row max == 0)
    __shared__ unsigned long long red[4];

    const float H = meta[0], W = meta[1];
    const int tid = threadIdx.x;

    if (blockIdx.x >= NANCHOR_BLOCKS) {
        // ---------- per-gt argmax path (windowed search over inside anchors) ----------
        const int g = blockIdx.x - NANCHOR_BLOCKS;
        const float gx1 = gt[4*g+0], gy1 = gt[4*g+1], gx2 = gt[4*g+2], gy2 = gt[4*g+3];
        const float area_b = (gx2 - gx1 + 1.0f) * (gy2 - gy1 + 1.0f);
        const int tx = tid & 15, ty = tid >> 4;

        constexpr int ibx1[9] = {-84,-176,-360,-56,-120,-248,-36,-80,-168};
        constexpr int iby1[9] = {-40,-88,-184,-56,-120,-248,-80,-168,-344};
        constexpr int ibx2[9] = { 99, 191, 375, 71, 135, 263, 51, 95, 183};
        constexpr int iby2[9] = { 55, 103, 199, 71, 135, 263, 95, 183, 359};
        constexpr int iarea[9] = {17664,70656,282624,16384,65536,262144,15488,61952,247808};

        unsigned long long best = 0ULL;  // < any real encoding
        #pragma unroll
        for (int a = 0; a < 9; ++a) {
            const int xlo_in = (-ibx1[a] + 15) >> 4;
            const int ylo_in = (-iby1[a] + 15) >> 4;
            const int xhi_in = (int)floorf((W - 1.0f - (float)ibx2[a]) * 0.0625f);
            const int yhi_in = (int)floorf((H - 1.0f - (float)iby2[a]) * 0.0625f);
            int xlo = max(max((int)floorf((gx1 - (float)ibx2[a]) * 0.0625f) - 1, xlo_in), 0);
            int xhi = min(min((int)floorf((gx2 - (float)ibx1[a]) * 0.0625f) + 1, xhi_in), 127);
            int ylo = max(max((int)floorf((gy1 - (float)iby2[a]) * 0.0625f) - 1, ylo_in), 0);
            int yhi = min(min((int)floorf((gy2 - (float)iby1[a]) * 0.0625f) + 1, yhi_in), 127);
            const float fa = (float)iarea[a];

            for (int iy = ylo + ty; iy <= yhi; iy += 16) {
                const float ay1 = (float)((iy << 4) + iby1[a]);
                const float ay2 = (float)((iy << 4) + iby2[a]);
                float ih = fminf(ay2, gy2) - fmaxf(ay1, gy1) + 1.0f; ih = fmaxf(ih, 0.0f);
                for (int ix = xlo + tx; ix <= xhi; ix += 16) {
                    const float ax1 = (float)((ix << 4) + ibx1[a]);
                    const float ax2 = (float)((ix << 4) + ibx2[a]);
                    bool inside = (ax1 >= 0.0f) & (ay1 >= 0.0f) & (ax2 < W) & (ay2 < H);
                    float iw = fminf(ax2, gx2) - fmaxf(ax1, gx1) + 1.0f; iw = fmaxf(iw, 0.0f);
                    float inter = iw * ih;
                    float uni = fmaxf(fa + area_b - inter, 1e-8f);
                    float iou = inter / uni;
                    float m = inside ? iou : -1.0f;
                    int n = ((iy << 7) + ix) * 9 + a;
                    unsigned long long e = ((unsigned long long)fenc(m) << 32) | (unsigned int)(~n);
                    if (e > best) best = e;
                }
            }
        }
        for (int off = 32; off >= 1; off >>= 1) {
            unsigned long long o = shfl_down_u64(best, off);
            if (o > best) best = o;
        }
        const int wave = tid >> 6, lane = tid & 63;
        if (lane == 0) red[wave] = best;
        __syncthreads();
        if (tid == 0) {
            unsigned long long v = red[0];
            if (red[1] > v) v = red[1];
            if (red[2] > v) v = red[2];
            if (red[3] > v) v = red[3];
            win[g] = (int)(~(unsigned int)(v & 0xffffffffULL));
        }
        return;
    }

    // ---------- per-anchor path: one type, one 16x16-cell tile ----------
    const int a  = blockIdx.x >> 6;          // anchor type, block-uniform
    const int t  = blockIdx.x & 63;          // tile id
    const int ix = ((t & 7) << 4) + (tid & 15);
    const int iy = ((t >> 3) << 4) + (tid >> 4);

    const float bx1 = c_bx1[a], by1 = c_by1[a], bx2 = c_bx2[a], by2 = c_by2[a];
    const float area_a = c_area[a];

    // Type-specific dilated tile bbox (tile px span + anchor extents + 4 pad):
    // gt outside it has inter == 0 exactly for every anchor in this block.
    {
        const float tx0 = (float)(((t & 7) << 8));        // tile px x base
        const float ty0 = (float)(((t >> 3) << 8));
        const float bbx1 = tx0 + bx1 - 4.0f;
        const float bbx2 = tx0 + 240.0f + bx2 + 4.0f;
        const float bby1 = ty0 + by1 - 4.0f;
        const float bby2 = ty0 + 240.0f + by2 + 4.0f;

        float4 b = ((const float4*)gt)[tid];
        if (tid == 0) sg0 = b;
        bool keep = (b.z >= bbx1) & (b.x <= bbx2) & (b.w >= bby1) & (b.y <= bby2);

        unsigned long long m = __ballot(keep);
        const int wave = tid >> 6, lane = tid & 63;
        const int my = __popcll(m & ((1ULL << lane) - 1ULL));
        if (lane == 0) wcnt[wave] = __popcll(m);
        __syncthreads();
        if (tid == 0) {
            int o = 0;
            #pragma unroll
            for (int w = 0; w < 4; ++w) { woff[w] = o; o += wcnt[w]; }
            sS = o;
        }
        __syncthreads();
        if (keep) {
            int p = woff[wave] + my;        // ascending original g across waves
            sbox[p] = b;
            sg[p] = tid;
        }
        __syncthreads();
    }
    const int S = sS;

    const float ax1 = (float)((ix << 4)) + bx1;
    const float ay1 = (float)((iy << 4)) + by1;
    const float ax2 = (float)((ix << 4)) + bx2;
    const float ay2 = (float)((iy << 4)) + by2;
    const bool inside = (ax1 >= 0.0f) & (ay1 >= 0.0f) & (ax2 < W) & (ay2 < H);

    float bestv = -1.0f;
    int bj = 0;
    for (int j = 0; j < S; ++j) {
        float4 bb = sbox[j];
        float iw = fminf(ax2, bb.z) - fmaxf(ax1, bb.x) + 1.0f; iw = fmaxf(iw, 0.0f);
        float ih = fminf(ay2, bb.w) - fmaxf(ay1, bb.y) + 1.0f; ih = fmaxf(ih, 0.0f);
        float inter = iw * ih;
        if (__any(inter > 0.0f)) {
            float areab = (bb.z - bb.x + 1.0f) * (bb.w - bb.y + 1.0f);  // == ref bitwise
            float uni = fmaxf(area_a + areab - inter, 1e-8f);
            float iou = inter / uni;          // lanes with inter==0 get exactly 0
            if (iou > bestv) { bestv = iou; bj = j; }   // strict > : first max
        }
        // skipped lanes/waves: iou == 0 candidates — folded into the
        // bestv<=0 fallback below (0 can only win an all-zero row).
    }
    // If bestv <= 0 the whole row's max is 0 (bestv==0 only arises from a
    // zero-inter lane inside an __any-taken iteration) -> jnp.argmax = 0.
    int barg; float4 gb;
    if (bestv <= 0.0f) { bestv = 0.0f; barg = 0; gb = sg0; }
    else               { barg = sg[bj]; gb = sbox[bj]; }
    (void)barg;

    // Label ladder minus the gt-argmax scatter (k_fix rewrites those anchors).
    float label = -1.0f;
    if (bestv < 0.3f) label = 0.0f;            // NEG_OVERLAP
    if (bestv >= 0.7f) label = 1.0f;           // POS_OVERLAP
    if (!inside) label = -1.0f;                // applied last

    float ew = ax2 - ax1 + 1.0f;
    float eh = ay2 - ay1 + 1.0f;
    float ecx = ax1 + 0.5f * ew;
    float ecy = ay1 + 0.5f * eh;
    float gw = gb.z - gb.x + 1.0f;
    float gh = gb.w - gb.y + 1.0f;
    float gcx = gb.x + 0.5f * gw;
    float gcy = gb.y + 0.5f * gh;
    float t0 = (gcx - ecx) / ew;
    float t1 = (gcy - ecy) / eh;
    float t2 = logf(gw / ew);
    float t3 = logf(gh / eh);
    if (!inside) { t0 = 0.0f; t1 = 0.0f; t2 = 0.0f; t3 = 0.0f; }

    const int n = ((iy << 7) + ix) * 9 + a;
    out[n] = label;
    ((float4*)(out + A_TOTAL))[n] = make_float4(t0, t1, t2, t3);
}

// Patch the 256 winner anchors (gt-argmax scatter-add). Winners are provably
// inside with iou > 0. gt + win staged in LDS (R3 lesson: single-block global
// uniform reads are latency-bound; R5/R6 lessons: fences/atomics worse than
// this tiny extra dispatch).
__global__ __launch_bounds__(256) void k_fix(
    const float* __restrict__ gt, const int* __restrict__ win,
    float* __restrict__ out)
{
    __shared__ float4 sb[G];
    __shared__ float  sa[G];
    __shared__ int    swin[G];
    const int t = threadIdx.x;
    {
        float4 b = ((const float4*)gt)[t];
        sb[t] = b;
        sa[t] = (b.z - b.x + 1.0f) * (b.w - b.y + 1.0f);
        swin[t] = win[t];
    }
    __syncthreads();

    const int idx = swin[t];
    int k = idx / 9;
    int a = idx - 9 * k;
    float sx = (float)((k & 127) << 4);
    float sy = (float)((k >> 7) << 4);
    float ax1 = sx + c_bx1[a];
    float ay1 = sy + c_by1[a];
    float ax2 = sx + c_bx2[a];
    float ay2 = sy + c_by2[a];
    float area_a = c_area[a];

    float mo = -1.0f;
    int cnt = 0;
    #pragma unroll 4
    for (int g = 0; g < G; ++g) {
        float4 bb = sb[g];
        float iw = fminf(ax2, bb.z) - fmaxf(ax1, bb.x) + 1.0f; iw = fmaxf(iw, 0.0f);
        float ih = fminf(ay2, bb.w) - fmaxf(ay1, bb.y) + 1.0f; ih = fmaxf(ih, 0.0f);
        float inter = iw * ih;
        float uni = fmaxf(area_a + sa[g] - inter, 1e-8f);
        float iou = inter / uni;
        mo = fmaxf(mo, iou);
        cnt += (swin[g] == idx);
    }

    float label = -1.0f;
    if (mo < 0.3f) label = 0.0f;
    label = label + (float)cnt * (1.0f - label);   // .at[].add with duplicates
    if (mo >= 0.7f) label = 1.0f;

    out[idx] = label;
}

extern "C" void kernel_launch(void* const* d_in, const int* in_sizes, int n_in,
                              void* d_out, int out_size, void* d_ws, size_t ws_size,
                              hipStream_t stream) {
    // d_in[0] = scores (unused), d_in[1] = gt_boxes (1,256,4), d_in[2] = metadata (1,3)
    const float* gt   = (const float*)d_in[1];
    const float* meta = (const float*)d_in[2];
    float* out = (float*)d_out;
    int* win = (int*)d_ws;   // 256 ints

    k_fused<<<TOTAL_BLOCKS, 256, 0, stream>>>(gt, meta, win, out);
    k_fix<<<1, 256, 0, stream>>>(gt, win, out);
}

// Round 8
// 84.146 us; speedup vs baseline: 1.9553x; 1.0804x over previous
//
#include <hip/hip_runtime.h>
#include <stdint.h>

#pragma clang fp contract(off)

#define A_TOTAL 147456   // 128*128*9
#define G 256
#define NANCHOR_BLOCKS 576          // 9 types x 64 tiles(16x16 cells)

// Base anchors (base_size=16, ratios {0.5,1,2}, scales {8,16,32}) — from
// reference _base_anchors() (np.round half-to-even: 11.5->12).
__constant__ float c_bx1[9] = { -84.f, -176.f, -360.f,  -56.f, -120.f, -248.f,  -36.f,  -80.f, -168.f };
__constant__ float c_by1[9] = { -40.f,  -88.f, -184.f,  -56.f, -120.f, -248.f,  -80.f, -168.f, -344.f };
__constant__ float c_bx2[9] = {  99.f,  191.f,  375.f,   71.f,  135.f,  263.f,   51.f,   95.f,  183.f };
__constant__ float c_by2[9] = {  55.f,  103.f,  199.f,   71.f,  135.f,  263.f,   95.f,  183.f,  359.f };
__constant__ float c_area[9] = { 17664.f, 70656.f, 282624.f, 16384.f, 65536.f, 262144.f, 15488.f, 61952.f, 247808.f };

__device__ __forceinline__ unsigned int fenc(float f) {
    unsigned int u = __float_as_uint(f);
    return (u & 0x80000000u) ? ~u : (u | 0x80000000u);
}

__device__ __forceinline__ unsigned long long shfl_down_u64(unsigned long long v, int off) {
    unsigned int lo = (unsigned int)v;
    unsigned int hi = (unsigned int)(v >> 32);
    lo = __shfl_down(lo, off, 64);
    hi = __shfl_down(hi, off, 64);
    return ((unsigned long long)hi << 32) | lo;
}

// D1: per-anchor path. Block b owns anchor type a=b>>6 over a 16x16-cell tile
// (type-uniform waves: scalar base coords, type-specific gt cull, uniform trip
// count, wave-level zero-skip). Writes the label ladder MINUS the gt-argmax
// scatter (D2 patches winners via atomicAdd) + bbox transform.
__global__ __launch_bounds__(256) void k_anchor(
    const float* __restrict__ gt, const float* __restrict__ meta,
    float* __restrict__ out)
{
    __shared__ float4 sbox[G];      // survivor boxes, ascending original g
    __shared__ int    wcnt[4], woff[4], sS;
    __shared__ float4 sg0;          // gt[0] (fallback when row max == 0)

    const float H = meta[0], W = meta[1];
    const int tid = threadIdx.x;

    const int a  = blockIdx.x >> 6;          // anchor type, block-uniform
    const int t  = blockIdx.x & 63;          // tile id
    const int ix = ((t & 7) << 4) + (tid & 15);
    const int iy = ((t >> 3) << 4) + (tid >> 4);

    const float bx1 = c_bx1[a], by1 = c_by1[a], bx2 = c_bx2[a], by2 = c_by2[a];
    const float area_a = c_area[a];

    // Type-specific dilated tile bbox: a gt outside it has inter == 0 exactly
    // for every anchor in this block (4 px pad > needed 1).
    {
        const float tx0 = (float)(((t & 7) << 8));
        const float ty0 = (float)(((t >> 3) << 8));
        const float bbx1 = tx0 + bx1 - 4.0f;
        const float bbx2 = tx0 + 240.0f + bx2 + 4.0f;
        const float bby1 = ty0 + by1 - 4.0f;
        const float bby2 = ty0 + 240.0f + by2 + 4.0f;

        float4 b = ((const float4*)gt)[tid];
        if (tid == 0) sg0 = b;
        bool keep = (b.z >= bbx1) & (b.x <= bbx2) & (b.w >= bby1) & (b.y <= bby2);

        unsigned long long m = __ballot(keep);
        const int wave = tid >> 6, lane = tid & 63;
        const int my = __popcll(m & ((1ULL << lane) - 1ULL));
        if (lane == 0) wcnt[wave] = __popcll(m);
        __syncthreads();
        if (tid == 0) {
            int o = 0;
            #pragma unroll
            for (int w = 0; w < 4; ++w) { woff[w] = o; o += wcnt[w]; }
            sS = o;
        }
        __syncthreads();
        if (keep) sbox[woff[wave] + my] = b;   // ascending original g
        __syncthreads();
    }
    const int S = sS;

    const float ax1 = (float)((ix << 4)) + bx1;
    const float ay1 = (float)((iy << 4)) + by1;
    const float ax2 = (float)((ix << 4)) + bx2;
    const float ay2 = (float)((iy << 4)) + by2;
    const bool inside = (ax1 >= 0.0f) & (ay1 >= 0.0f) & (ax2 < W) & (ay2 < H);

    float bestv = -1.0f;
    int bj = 0;
    for (int j = 0; j < S; ++j) {
        float4 bb = sbox[j];
        float iw = fminf(ax2, bb.z) - fmaxf(ax1, bb.x) + 1.0f; iw = fmaxf(iw, 0.0f);
        float ih = fminf(ay2, bb.w) - fmaxf(ay1, bb.y) + 1.0f; ih = fmaxf(ih, 0.0f);
        float inter = iw * ih;
        if (__any(inter > 0.0f)) {
            float areab = (bb.z - bb.x + 1.0f) * (bb.w - bb.y + 1.0f);  // == ref bitwise
            float uni = fmaxf(area_a + areab - inter, 1e-8f);
            float iou = inter / uni;          // lanes with inter==0 get exactly 0
            if (iou > bestv) { bestv = iou; bj = j; }   // strict > : first max
        }
    }
    // Culled/skipped gts have iou exactly 0. If bestv <= 0 the whole row's
    // max is 0 and iou[0]==0 -> jnp.argmax = 0.
    float4 gb;
    if (bestv <= 0.0f) { bestv = 0.0f; gb = sg0; }
    else               { gb = sbox[bj]; }

    // Label ladder minus the gt-argmax scatter.
    float label = -1.0f;
    if (bestv < 0.3f) label = 0.0f;            // NEG_OVERLAP
    if (bestv >= 0.7f) label = 1.0f;           // POS_OVERLAP
    if (!inside) label = -1.0f;                // applied last

    float ew = ax2 - ax1 + 1.0f;
    float eh = ay2 - ay1 + 1.0f;
    float ecx = ax1 + 0.5f * ew;
    float ecy = ay1 + 0.5f * eh;
    float gw = gb.z - gb.x + 1.0f;
    float gh = gb.w - gb.y + 1.0f;
    float gcx = gb.x + 0.5f * gw;
    float gcy = gb.y + 0.5f * gh;
    float t0 = (gcx - ecx) / ew;
    float t1 = (gcy - ecy) / eh;
    float t2 = logf(gw / ew);
    float t3 = logf(gh / eh);
    if (!inside) { t0 = 0.0f; t1 = 0.0f; t2 = 0.0f; t3 = 0.0f; }

    const int n = ((iy << 7) + ix) * 9 + a;
    out[n] = label;
    ((float4*)(out + A_TOTAL))[n] = make_float4(t0, t1, t2, t3);
}

// D2: one block per gt. (1) windowed argmax over inside anchors -> winner w
// (u64 encode: first-max-index semantics). (2) block-wide mo(w) = max iou of
// w against ALL gts (one gt per lane, identical per-pair arithmetic -> bitwise
// == reference row max). (3) thread 0: the reference scatter-add
// labels.at[w].add(1 - labels[w]) gathers ORIGINAL labels, so each gt
// contributes (1 - o(w)) with o(w) = (mo<0.3 ? 0 : -1) purely local; when
// mo >= 0.7 the final override forces 1, which D1 already wrote -> no-op.
// atomicAdd is exact (small ints in fp32) and commutative across duplicate
// winners. D1's stores are visible (kernel boundary). No fences, no ws.
__global__ __launch_bounds__(256) void k_gt(
    const float* __restrict__ gt, const float* __restrict__ meta,
    float* __restrict__ out)
{
    __shared__ float4 sGT[G];
    __shared__ unsigned long long red[4];
    __shared__ float mred[4];

    const int g = blockIdx.x;
    const int tid = threadIdx.x;
    sGT[tid] = ((const float4*)gt)[tid];
    __syncthreads();

    const float4 me = sGT[g];
    const float gx1 = me.x, gy1 = me.y, gx2 = me.z, gy2 = me.w;
    const float area_b = (gx2 - gx1 + 1.0f) * (gy2 - gy1 + 1.0f);
    const float H = meta[0], W = meta[1];
    const int tx = tid & 15, ty = tid >> 4;

    constexpr int ibx1[9] = {-84,-176,-360,-56,-120,-248,-36,-80,-168};
    constexpr int iby1[9] = {-40,-88,-184,-56,-120,-248,-80,-168,-344};
    constexpr int ibx2[9] = { 99, 191, 375, 71, 135, 263, 51, 95, 183};
    constexpr int iby2[9] = { 55, 103, 199, 71, 135, 263, 95, 183, 359};
    constexpr int iarea[9] = {17664,70656,282624,16384,65536,262144,15488,61952,247808};

    unsigned long long best = 0ULL;  // < any real encoding
    #pragma unroll
    for (int a = 0; a < 9; ++a) {
        const int xlo_in = (-ibx1[a] + 15) >> 4;
        const int ylo_in = (-iby1[a] + 15) >> 4;
        const int xhi_in = (int)floorf((W - 1.0f - (float)ibx2[a]) * 0.0625f);
        const int yhi_in = (int)floorf((H - 1.0f - (float)iby2[a]) * 0.0625f);
        int xlo = max(max((int)floorf((gx1 - (float)ibx2[a]) * 0.0625f) - 1, xlo_in), 0);
        int xhi = min(min((int)floorf((gx2 - (float)ibx1[a]) * 0.0625f) + 1, xhi_in), 127);
        int ylo = max(max((int)floorf((gy1 - (float)iby2[a]) * 0.0625f) - 1, ylo_in), 0);
        int yhi = min(min((int)floorf((gy2 - (float)iby1[a]) * 0.0625f) + 1, yhi_in), 127);
        const float fa = (float)iarea[a];

        for (int iy = ylo + ty; iy <= yhi; iy += 16) {
            const float ay1 = (float)((iy << 4) + iby1[a]);
            const float ay2 = (float)((iy << 4) + iby2[a]);
            float ih = fminf(ay2, gy2) - fmaxf(ay1, gy1) + 1.0f; ih = fmaxf(ih, 0.0f);
            for (int ix = xlo + tx; ix <= xhi; ix += 16) {
                const float ax1 = (float)((ix << 4) + ibx1[a]);
                const float ax2 = (float)((ix << 4) + ibx2[a]);
                bool inside = (ax1 >= 0.0f) & (ay1 >= 0.0f) & (ax2 < W) & (ay2 < H);
                float iw = fminf(ax2, gx2) - fmaxf(ax1, gx1) + 1.0f; iw = fmaxf(iw, 0.0f);
                float inter = iw * ih;
                float uni = fmaxf(fa + area_b - inter, 1e-8f);
                float iou = inter / uni;
                float m = inside ? iou : -1.0f;
                int n = ((iy << 7) + ix) * 9 + a;
                unsigned long long e = ((unsigned long long)fenc(m) << 32) | (unsigned int)(~n);
                if (e > best) best = e;
            }
        }
    }
    for (int off = 32; off >= 1; off >>= 1) {
        unsigned long long o = shfl_down_u64(best, off);
        if (o > best) best = o;
    }
    const int wave = tid >> 6, lane = tid & 63;
    if (lane == 0) red[wave] = best;
    __syncthreads();
    // broadcast winner to all threads via LDS
    if (tid == 0) {
        unsigned long long v = red[0];
        if (red[1] > v) v = red[1];
        if (red[2] > v) v = red[2];
        if (red[3] > v) v = red[3];
        red[0] = v;
    }
    __syncthreads();
    const int w = (int)(~(unsigned int)(red[0] & 0xffffffffULL));

    // mo(w): one gt per lane, identical per-pair arithmetic as everywhere.
    int k = w / 9;
    int a = w - 9 * k;
    float ax1 = (float)(((k & 127) << 4)) + c_bx1[a];
    float ay1 = (float)(((k >> 7) << 4)) + c_by1[a];
    float ax2 = (float)(((k & 127) << 4)) + c_bx2[a];
    float ay2 = (float)(((k >> 7) << 4)) + c_by2[a];
    float area_a = c_area[a];

    float4 bb = sGT[tid];
    float iw = fminf(ax2, bb.z) - fmaxf(ax1, bb.x) + 1.0f; iw = fmaxf(iw, 0.0f);
    float ih = fminf(ay2, bb.w) - fmaxf(ay1, bb.y) + 1.0f; ih = fmaxf(ih, 0.0f);
    float inter = iw * ih;
    float areab = (bb.z - bb.x + 1.0f) * (bb.w - bb.y + 1.0f);
    float uni = fmaxf(area_a + areab - inter, 1e-8f);
    float mo = inter / uni;
    for (int off = 32; off >= 1; off >>= 1) mo = fmaxf(mo, __shfl_down(mo, off, 64));
    if (lane == 0) mred[wave] = mo;
    __syncthreads();
    if (tid == 0) {
        float m = fmaxf(fmaxf(mred[0], mred[1]), fmaxf(mred[2], mred[3]));
        if (m < 0.7f) {
            float o = (m < 0.3f) ? 0.0f : -1.0f;   // D1 wrote exactly this
            atomicAdd(&out[w], 1.0f - o);          // ref: add(1 - labels[w])
        }
        // m >= 0.7: D1 already wrote 1 (the >=POS override) -> no-op.
    }
}

extern "C" void kernel_launch(void* const* d_in, const int* in_sizes, int n_in,
                              void* d_out, int out_size, void* d_ws, size_t ws_size,
                              hipStream_t stream) {
    // d_in[0] = scores (unused), d_in[1] = gt_boxes (1,256,4), d_in[2] = metadata (1,3)
    const float* gt   = (const float*)d_in[1];
    const float* meta = (const float*)d_in[2];
    float* out = (float*)d_out;

    k_anchor<<<NANCHOR_BLOCKS, 256, 0, stream>>>(gt, meta, out);
    k_gt<<<G, 256, 0, stream>>>(gt, meta, out);
}